// Round 5
// baseline (587.625 us; speedup 1.0000x reference)
//
#include <hip/hip_runtime.h>
#include <math.h>

#define NROWS 8192
#define DDIM  4096
#define NEXP  64
#define BROWS 128          // rows per block
#define BK    16           // k-depth per staged tile
#define XS_STRIDE 20       // 20*4B: 16B-aligned float4 rows, 2-way banks (free)
#define WS_STRIDE 68       // 68*4B: 16B-aligned, banks 4k+e (2-way, free)

// Block = 64 threads (1 wave): 16 row-groups x 4 expert-groups.
// Thread tile: 8 rows x 16 experts (acc = 128 VGPR).
// amdgpu_waves_per_eu(2,2): allocator targets exactly 2 waves/EU -> 256 VGPR
// budget -> full live set (acc128 + prefetch48 + inner48) fits, prefetch regs
// survive across compute (R3/R4: 144-VGPR squeeze sank the loads to their use,
// exposing full memory latency at 1 wave/SIMD -> VALUBusy 16%).
// ksplit=32 -> 2048 waves = 8/CU = 2/SIMD for latency overlap.
__global__ __launch_bounds__(64)
__attribute__((amdgpu_waves_per_eu(2, 2)))
void gemm_partial_kernel(
    const float* __restrict__ x, const float* __restrict__ w,
    float* __restrict__ part, int ksplit)
{
    __shared__ float xs[BROWS][XS_STRIDE];
    __shared__ float wt[BK][WS_STRIDE];

    const int l  = threadIdx.x;        // 0..63
    const int tr = l >> 2;             // 0..15 row group
    const int te = l & 3;              // 0..3 expert group (16 experts each)
    const int r0 = blockIdx.x * BROWS;
    const int kh = blockIdx.y;
    const int kchunk = DDIM / ksplit;
    const int k0 = kh * kchunk;
    const int niter = kchunk / BK;

    // x staging: rows tr+16j, k-quad te*4 (16 lines / instr, coalesced 64B)
    const int skc = te * 4;
    const float* xp = x + (size_t)(r0 + tr) * DDIM + k0 + skc;
    // W staging: lane = (expert e = l>>2, k-quad kq = l&3): 16 lines / instr
    const int we = l >> 2;             // 0..15 (expert base, +16*u per load)
    const int wq = (l & 3) * 4;        // k offset 0,4,8,12
    const float* wp = w + (size_t)we * DDIM + k0 + wq;

    float acc[8][16];
#pragma unroll
    for (int i = 0; i < 8; i++)
#pragma unroll
        for (int j = 0; j < 16; j++) acc[i][j] = 0.f;

    float4 stx[8], stw[4];
#pragma unroll
    for (int j = 0; j < 8; j++) stx[j] = *(const float4*)(xp + (size_t)16 * j * DDIM);
#pragma unroll
    for (int u = 0; u < 4; u++) stw[u] = *(const float4*)(wp + (size_t)16 * u * DDIM);

    for (int kt = 0; kt < niter; kt++) {
        __syncthreads();               // single-wave block: effectively free
#pragma unroll
        for (int j = 0; j < 8; j++) *(float4*)&xs[tr + 16 * j][skc] = stx[j];
#pragma unroll
        for (int u = 0; u < 4; u++) { // wt[k][e] transposed scatter, 2-way banks
            wt[wq + 0][we + 16 * u] = stw[u].x;
            wt[wq + 1][we + 16 * u] = stw[u].y;
            wt[wq + 2][we + 16 * u] = stw[u].z;
            wt[wq + 3][we + 16 * u] = stw[u].w;
        }
        __syncthreads();

        if (kt + 1 < niter) {          // prefetch next tile into regs
            const float* xpn = xp + (kt + 1) * BK;
            const float* wpn = wp + (kt + 1) * BK;
#pragma unroll
            for (int j = 0; j < 8; j++) stx[j] = *(const float4*)(xpn + (size_t)16 * j * DDIM);
#pragma unroll
            for (int u = 0; u < 4; u++) stw[u] = *(const float4*)(wpn + (size_t)16 * u * DDIM);
        }

#pragma unroll
        for (int kk = 0; kk < BK; kk += 4) {
            float4 xa[8];
#pragma unroll
            for (int i = 0; i < 8; i++) xa[i] = *(const float4*)&xs[tr + 16 * i][kk];
#pragma unroll
            for (int k2 = 0; k2 < 4; k2++) {
                const float* wr = &wt[kk + k2][te * 16];
                const float4 w0 = *(const float4*)(wr + 0);
                const float4 w1 = *(const float4*)(wr + 4);
                const float4 w2 = *(const float4*)(wr + 8);
                const float4 w3 = *(const float4*)(wr + 12);
#pragma unroll
                for (int i = 0; i < 8; i++) {
                    const float xv = ((const float*)&xa[i])[k2];
                    acc[i][0]  += xv * w0.x;  acc[i][1]  += xv * w0.y;
                    acc[i][2]  += xv * w0.z;  acc[i][3]  += xv * w0.w;
                    acc[i][4]  += xv * w1.x;  acc[i][5]  += xv * w1.y;
                    acc[i][6]  += xv * w1.z;  acc[i][7]  += xv * w1.w;
                    acc[i][8]  += xv * w2.x;  acc[i][9]  += xv * w2.y;
                    acc[i][10] += xv * w2.z;  acc[i][11] += xv * w2.w;
                    acc[i][12] += xv * w3.x;  acc[i][13] += xv * w3.y;
                    acc[i][14] += xv * w3.z;  acc[i][15] += xv * w3.w;
                }
            }
        }
    }

    float* po = part + ((size_t)kh * NROWS + r0) * NEXP;
#pragma unroll
    for (int i = 0; i < 8; i++)
#pragma unroll
        for (int u = 0; u < 4; u++)
            *(float4*)&po[(size_t)(tr + 16 * i) * NEXP + te * 16 + 4 * u] =
                make_float4(acc[i][4 * u], acc[i][4 * u + 1],
                            acc[i][4 * u + 2], acc[i][4 * u + 3]);
}

// One wave per row: sum split-K partials, sigmoid, +bias, top-2 (tie -> lower
// index), normalize. out: [weights 2N][indices-as-float 2N][scores 64N]
__global__ __launch_bounds__(256) void gate_topk_kernel(
    const float* __restrict__ part, const float* __restrict__ bias,
    float* __restrict__ out, int ksplit)
{
    const int tid = threadIdx.x;
    const int e   = tid & 63;
    const int row = blockIdx.x * 4 + (tid >> 6);
    const size_t idx = (size_t)row * NEXP + e;

    float logit = 0.f;
    for (int s = 0; s < ksplit; s++)
        logit += part[(size_t)s * NROWS * NEXP + idx];
    const float score = 1.0f / (1.0f + expf(-logit));
    out[(size_t)4 * NROWS + idx] = score;           // scores

    const float biased = score + bias[e];

    float v = biased; int bi = e;
#pragma unroll
    for (int off = 32; off; off >>= 1) {
        const float ov = __shfl_xor(v, off);
        const int   oi = __shfl_xor(bi, off);
        if (ov > v || (ov == v && oi < bi)) { v = ov; bi = oi; }
    }
    const int i1 = bi;

    float v2 = (e == i1) ? -INFINITY : biased;
    int bi2 = e;
#pragma unroll
    for (int off = 32; off; off >>= 1) {
        const float ov = __shfl_xor(v2, off);
        const int   oi = __shfl_xor(bi2, off);
        if (ov > v2 || (ov == v2 && oi < bi2)) { v2 = ov; bi2 = oi; }
    }
    const int i2 = bi2;

    const float s1 = __shfl(score, i1);
    const float s2 = __shfl(score, i2);
    if (e == 0) {
        const float inv = 1.0f / (s1 + s2);
        out[(size_t)row * 2 + 0] = s1 * inv;
        out[(size_t)row * 2 + 1] = s2 * inv;
        out[(size_t)2 * NROWS + row * 2 + 0] = (float)i1;
        out[(size_t)2 * NROWS + row * 2 + 1] = (float)i2;
    }
}

extern "C" void kernel_launch(void* const* d_in, const int* in_sizes, int n_in,
                              void* d_out, int out_size, void* d_ws, size_t ws_size,
                              hipStream_t stream)
{
    const float* x    = (const float*)d_in[0];
    const float* w    = (const float*)d_in[1];
    const float* bias = (const float*)d_in[2];
    float* out  = (float*)d_out;
    float* part = (float*)d_ws;

    // split-K: 32 preferred (2048 single-wave blocks = 8 waves/CU = 2/SIMD)
    int ksplit = 32;
    while (ksplit > 1 && (size_t)ksplit * NROWS * NEXP * 4 > ws_size) ksplit >>= 1;

    dim3 g1(NROWS / BROWS, ksplit);
    gemm_partial_kernel<<<g1, 64, 0, stream>>>(x, w, part, ksplit);
    gate_topk_kernel<<<NROWS / 4, 256, 0, stream>>>(part, bias, out, ksplit);
}

// Round 6
// 221.525 us; speedup vs baseline: 2.6526x; 2.6526x over previous
//
#include <hip/hip_runtime.h>
#include <hip/hip_bf16.h>
#include <math.h>

#define NROWS 8192
#define DDIM  4096
#define NEXP  64
#define KSPLIT 8
#define KCHUNK (DDIM / KSPLIT)   // 512
#define KSTEPS (KCHUNK / 32)     // 16

typedef __attribute__((ext_vector_type(8))) short bf16x8;
typedef __attribute__((ext_vector_type(4))) float f32x4;

__device__ inline unsigned short bf16_rne(float f) {
    unsigned u = __builtin_bit_cast(unsigned, f);
    u += 0x7FFF + ((u >> 16) & 1);
    return (unsigned short)(u >> 16);
}

// split 8 fp32 -> hi/lo bf16 fragments (x = hi + lo + r, |r| <= 2^-18|x|)
__device__ inline void split8(const float* xf, bf16x8& hi, bf16x8& lo) {
#pragma unroll
    for (int j = 0; j < 8; j++) {
        const unsigned short h = bf16_rne(xf[j]);
        const float hf = __builtin_bit_cast(float, (unsigned)h << 16);
        hi[j] = (short)h;
        lo[j] = (short)bf16_rne(xf[j] - hf);
    }
}

// Preconvert W (64 x 4096 fp32) into MFMA B-fragment-linear bf16 hi/lo:
// frag element j of lane l, tile t, k-chunk kc  =  B[k=kc*32+(l>>4)*8+j][n=t*16+(l&15)]
// stored at ((kc*4+t)*64+l)*8. One-time ~1 MB -> L2-resident for the GEMM.
__global__ __launch_bounds__(256) void wfrag_kernel(
    const float* __restrict__ w, unsigned short* __restrict__ whi,
    unsigned short* __restrict__ wlo)
{
    const int kc = blockIdx.x;            // 0..127
    const int t  = threadIdx.x >> 6;      // n-tile 0..3
    const int l  = threadIdx.x & 63;
    const int e  = t * 16 + (l & 15);
    const int k0 = kc * 32 + ((l >> 4) * 8);
    const float* p = w + (size_t)e * DDIM + k0;
    float xf[8];
    *(float4*)&xf[0] = *(const float4*)p;
    *(float4*)&xf[4] = *(const float4*)(p + 4);
    bf16x8 hi, lo;
    split8(xf, hi, lo);
    const size_t off = ((size_t)(kc * 4 + t) * 64 + l) * 8;
    *(bf16x8*)(whi + off) = hi;
    *(bf16x8*)(wlo + off) = lo;
}

// GEMM: no LDS, no barriers. Block = 4 waves; wave = 16-row stripe x 64 experts.
// Per k-step(32): 2 dwordx4 x-loads (fp32, converted in-reg) + 8 b128 B-loads
// (L2) + 12 MFMA 16x16x32 (hh, hl, lh). acc = 16 VGPR; live set ~120 regs.
__global__ __launch_bounds__(256) void gemm_partial_kernel(
    const float* __restrict__ x, const unsigned short* __restrict__ whi,
    const unsigned short* __restrict__ wlo, float* __restrict__ part)
{
    const int tid = threadIdx.x;
    const int wv  = tid >> 6;           // wave -> m-stripe
    const int l   = tid & 63;
    const int q   = l >> 4;             // quad
    const int r0  = blockIdx.x * 64 + wv * 16;
    const int kh  = blockIdx.y;
    const int kb  = kh * KCHUNK;

    // A: lane holds A[m=l&15][k=q*8+j]
    const float* xp = x + (size_t)(r0 + (l & 15)) * DDIM + kb + q * 8;
    // B frags: base for this k-range, this lane
    const unsigned short* bhp = whi + ((size_t)(kb / 32) * 4 * 64 + l) * 8;
    const unsigned short* blp = wlo + ((size_t)(kb / 32) * 4 * 64 + l) * 8;

    f32x4 acc[4] = {f32x4{0,0,0,0}, f32x4{0,0,0,0}, f32x4{0,0,0,0}, f32x4{0,0,0,0}};

    float  xf[2][8];
    bf16x8 bh[2][4], bl[2][4];

    // prefetch step 0
    *(float4*)&xf[0][0] = *(const float4*)(xp);
    *(float4*)&xf[0][4] = *(const float4*)(xp + 4);
#pragma unroll
    for (int t = 0; t < 4; t++) {
        bh[0][t] = *(const bf16x8*)(bhp + (size_t)t * 64 * 8);
        bl[0][t] = *(const bf16x8*)(blp + (size_t)t * 64 * 8);
    }

    for (int s = 0; s < KSTEPS; s++) {
        const int cur = s & 1, nxt = cur ^ 1;
        if (s + 1 < KSTEPS) {           // prefetch next step
            const float* xpn = xp + (s + 1) * 32;
            const unsigned short* bhn = bhp + (size_t)(s + 1) * 4 * 64 * 8;
            const unsigned short* bln = blp + (size_t)(s + 1) * 4 * 64 * 8;
            *(float4*)&xf[nxt][0] = *(const float4*)(xpn);
            *(float4*)&xf[nxt][4] = *(const float4*)(xpn + 4);
#pragma unroll
            for (int t = 0; t < 4; t++) {
                bh[nxt][t] = *(const bf16x8*)(bhn + (size_t)t * 64 * 8);
                bl[nxt][t] = *(const bf16x8*)(bln + (size_t)t * 64 * 8);
            }
        }
        bf16x8 ahi, alo;
        split8(xf[cur], ahi, alo);
#pragma unroll
        for (int t = 0; t < 4; t++) {
            acc[t] = __builtin_amdgcn_mfma_f32_16x16x32_bf16(ahi, bh[cur][t], acc[t], 0, 0, 0);
            acc[t] = __builtin_amdgcn_mfma_f32_16x16x32_bf16(ahi, bl[cur][t], acc[t], 0, 0, 0);
            acc[t] = __builtin_amdgcn_mfma_f32_16x16x32_bf16(alo, bh[cur][t], acc[t], 0, 0, 0);
        }
    }

    // C/D: row = q*4 + r, col = l&15  (m89-verified mapping)
    float* po = part + (size_t)kh * NROWS * NEXP;
#pragma unroll
    for (int t = 0; t < 4; t++)
#pragma unroll
        for (int r = 0; r < 4; r++)
            po[(size_t)(r0 + q * 4 + r) * NEXP + t * 16 + (l & 15)] = acc[t][r];
}

// One wave per row: sum split-K partials, sigmoid, +bias, top-2 (tie -> lower
// index), normalize. out: [weights 2N][indices-as-float 2N][scores 64N]
__global__ __launch_bounds__(256) void gate_topk_kernel(
    const float* __restrict__ part, const float* __restrict__ bias,
    float* __restrict__ out)
{
    const int tid = threadIdx.x;
    const int e   = tid & 63;
    const int row = blockIdx.x * 4 + (tid >> 6);
    const size_t idx = (size_t)row * NEXP + e;

    float logit = 0.f;
#pragma unroll
    for (int s = 0; s < KSPLIT; s++)
        logit += part[(size_t)s * NROWS * NEXP + idx];
    const float score = 1.0f / (1.0f + expf(-logit));
    out[(size_t)4 * NROWS + idx] = score;           // scores

    const float biased = score + bias[e];

    float v = biased; int bi = e;
#pragma unroll
    for (int off = 32; off; off >>= 1) {
        const float ov = __shfl_xor(v, off);
        const int   oi = __shfl_xor(bi, off);
        if (ov > v || (ov == v && oi < bi)) { v = ov; bi = oi; }
    }
    const int i1 = bi;

    float v2 = (e == i1) ? -INFINITY : biased;
    int bi2 = e;
#pragma unroll
    for (int off = 32; off; off >>= 1) {
        const float ov = __shfl_xor(v2, off);
        const int   oi = __shfl_xor(bi2, off);
        if (ov > v2 || (ov == v2 && oi < bi2)) { v2 = ov; bi2 = oi; }
    }
    const int i2 = bi2;

    const float s1 = __shfl(score, i1);
    const float s2 = __shfl(score, i2);
    if (e == 0) {
        const float inv = 1.0f / (s1 + s2);
        out[(size_t)row * 2 + 0] = s1 * inv;
        out[(size_t)row * 2 + 1] = s2 * inv;
        out[(size_t)2 * NROWS + row * 2 + 0] = (float)i1;
        out[(size_t)2 * NROWS + row * 2 + 1] = (float)i2;
    }
}

extern "C" void kernel_launch(void* const* d_in, const int* in_sizes, int n_in,
                              void* d_out, int out_size, void* d_ws, size_t ws_size,
                              hipStream_t stream)
{
    const float* x    = (const float*)d_in[0];
    const float* w    = (const float*)d_in[1];
    const float* bias = (const float*)d_in[2];
    float* out  = (float*)d_out;

    float* part = (float*)d_ws;                                      // 16 MB
    const size_t part_bytes = (size_t)KSPLIT * NROWS * NEXP * 4;
    unsigned short* whi = (unsigned short*)((char*)d_ws + part_bytes);          // 512 KB
    unsigned short* wlo = (unsigned short*)((char*)d_ws + part_bytes + (size_t)NEXP * DDIM * 2);

    wfrag_kernel<<<DDIM / 32, 256, 0, stream>>>(w, whi, wlo);
    dim3 g1(NROWS / 64, KSPLIT);
    gemm_partial_kernel<<<g1, 256, 0, stream>>>(x, whi, wlo, part);
    gate_topk_kernel<<<NROWS / 4, 256, 0, stream>>>(part, bias, out);
}